// Round 16
// baseline (97.003 us; speedup 1.0000x reference)
//
#include <hip/hip_runtime.h>
#include <math.h>

#define HH   128
#define WW   128
#define HWP  16384      // H*W
#define CIN  64
#define COUT 128

typedef float  f32x4  __attribute__((ext_vector_type(4)));
typedef short  short8 __attribute__((ext_vector_type(8)));

// ws layout (bytes): wbf [128][576] bf16 @0 (147456); owbf [32][576] bf16 @147456
// (73728); xt NHWC bf16 [4*16384][64] @221184 (8388608). NEED = 8609792.
#define WBF_B   ((size_t)0)
#define OWBF_B  ((size_t)147456)
#define XT_B    ((size_t)221184)
#define WS_NEED ((size_t)8609792)

__device__ inline unsigned short f2bf(float f) {
    unsigned u = __builtin_bit_cast(unsigned, f);
    return (unsigned short)((u + 0x7FFFu + ((u >> 16) & 1u)) >> 16);   // RNE
}

// ---------------- prep: bf16 weight transposes ----------------
__global__ __launch_bounds__(256) void k_prep_w(const float* __restrict__ wgt,
                                                const float* __restrict__ ow,
                                                unsigned short* __restrict__ wbf,
                                                unsigned short* __restrict__ owbf) {
    int tid = blockIdx.x * 256 + threadIdx.x;   // 288*256 = 73728 exactly
    {
        int oc = tid / 576;
        int r  = tid - oc * 576;
        int kk = r >> 6;
        int c  = r & 63;
        wbf[tid] = f2bf(wgt[((size_t)oc * CIN + c) * 9 + kk]);
    }
    if (tid < 32 * 576) {
        int oc  = tid / 576;
        int r   = tid - oc * 576;
        int tap = r >> 6;
        int c   = r & 63;
        owbf[tid] = (oc < 27) ? f2bf(ow[((size_t)oc * CIN + c) * 9 + tap]) : 0;
    }
}

// ---------------- prep: x NCHW fp32 -> NHWC bf16 ----------------
__global__ __launch_bounds__(256) void k_xt(const float* __restrict__ x,
                                            unsigned short* __restrict__ xt) {
    int t = threadIdx.x;
    int cgrp = t & 7, px = t >> 3;            // px 0..31
    int pix = blockIdx.x * 32 + px;           // grid 2048
    int b = pix >> 14, hw = pix & 16383;
    const float* xp = x + (size_t)b * CIN * HWP + (size_t)(cgrp * 8) * HWP + hw;
    unsigned pk[4];
#pragma unroll
    for (int d = 0; d < 4; ++d) {
        float lo = xp[(size_t)(2 * d) * HWP];
        float hi = xp[(size_t)(2 * d + 1) * HWP];
        pk[d] = (unsigned)f2bf(lo) | ((unsigned)f2bf(hi) << 16);
    }
    *(uint4*)(xt + (size_t)pix * 64 + cgrp * 8) = *(uint4*)pk;
}

// ================= v2: NHWC-bf16 fused kernel (R11 structure) =================
// block = 32 pixels of one row x all 128 oc; 256 threads; LDS 11.6 KB
// R16: XCD-aware swizzle (T1). Round-robin dispatch puts consecutive blockIdx
// on different XCDs; remap so XCD k = blockIdx%8 owns the contiguous tile
// chunk [k*256, (k+1)*256) = one batch-half (64 h-rows + halo ~= 1.06 MB of
// xt) -> corner gathers hit the XCD-private 4MB L2 (~200cy) instead of
// L3/HBM (~600-900cy). Bijective: 2048 % 8 == 0.
__global__ __launch_bounds__(256) void k_fused_v2(const unsigned short* __restrict__ xt,
                                                  const unsigned short* __restrict__ wbf,
                                                  const unsigned short* __restrict__ owbf,
                                                  const float* __restrict__ ob,
                                                  const float* __restrict__ bias,
                                                  float* __restrict__ out) {
    __shared__ __align__(16) char smem[11648];
    char*  mbase  = smem;                    // 2 x 4KB bf16 [32p][64k] swizzled dbuf
    float* meta_s = (float*)(smem + 8192);   // [comp][kk][p] 3456B

    int blk0 = blockIdx.x;                // 2048
    int blk  = (blk0 & 7) * 256 + (blk0 >> 3);   // T1 XCD chunking
    int b   = blk >> 9;
    int rem = blk & 511;
    int h   = rem >> 2;
    int w0  = (rem & 3) << 5;
    int t   = threadIdx.x;

    int p1 = t >> 3;                      // pixel in tile (staging role)
    int cg = t & 7;                       // 8-channel group (staging role)
    int l  = t & 63;
    int wid = t >> 6;                     // wave id
    int lm = l & 15, lk = l >> 4;

    const unsigned short* xbt = xt + (size_t)b * HWP * 64;

    // ===== stage A: offset conv, B-frags DIRECT from global xt (no LDS) =====
    int ocf = wid >> 1, pxf = wid & 1;    // wave quadrant: oc[ocf*16+), px[pxf*16+)
    int spx = pxf * 16 + lm;
    f32x4 sacc = {0.f, 0.f, 0.f, 0.f};
    const unsigned short* sab = owbf + (size_t)(ocf * 16 + lm) * 576 + lk * 8;

#pragma unroll
    for (int tap = 0; tap < 9; ++tap) {
        int ky = tap / 3, kx = tap % 3;
        int yy = h - 1 + ky;
        int xx = w0 - 1 + kx + spx;
        bool vld = (yy >= 0) && (yy < HH) && (xx >= 0) && (xx < WW);
        int yc = min(max(yy, 0), HH - 1), xc = min(max(xx, 0), WW - 1);
        const unsigned short* bp = xbt + (size_t)(yc * WW + xc) * 64 + lk * 8;
#pragma unroll
        for (int ch = 0; ch < 2; ++ch) {
            short8 a = *(const short8*)(sab + tap * 64 + ch * 32);
            uint4 v = *(const uint4*)(bp + ch * 32);
            v.x = vld ? v.x : 0u;  v.y = vld ? v.y : 0u;
            v.z = vld ? v.z : 0u;  v.w = vld ? v.w : 0u;
            sacc = __builtin_amdgcn_mfma_f32_16x16x32_bf16(a, __builtin_bit_cast(short8, v), sacc, 0, 0, 0);
        }
    }
    // postprocess own quadrant -> meta_s (C map: col=lane&15 -> px, row=lk*4+r -> oc)
#pragma unroll
    for (int r = 0; r < 4; ++r) {
        int oc = ocf * 16 + lk * 4 + r;
        if (oc < 27) {
            float v = sacc[r] + ob[oc];
            if (oc < 18) {
                meta_s[(oc & 1) * 288 + (oc >> 1) * 32 + spx] = v;
            } else {
                meta_s[2 * 288 + (oc - 18) * 32 + spx] = 1.f / (1.f + expf(-v));
            }
        }
    }
    __syncthreads();   // meta_s ready

    // ================= main: pipelined bilinear (bf16x8 corners) -> MFMA =======
    f32x4 acc00 = {0.f,0.f,0.f,0.f};
    f32x4 acc01 = {0.f,0.f,0.f,0.f};
    f32x4 acc10 = {0.f,0.f,0.f,0.f};
    f32x4 acc11 = {0.f,0.f,0.f,0.f};

    const unsigned short* arow0 = wbf + (size_t)(wid * 32 + lm) * 576 + lk * 8;
    const unsigned short* arow1 = arow0 + 16 * 576;

    int pA = lm, pB = lm + 16;
    int rbA = pA * 128, rbB = pB * 128;
    int swA = pA & 7,   swB = pB & 7;

    // SINGLE-SLOT pipeline registers (R15)
    uint4 cc00, cc01, cc10, cc11;
    float cw00, cw01, cw10, cw11;

    const unsigned short* xbc = xbt + cg * 8;   // this thread's channel slice

#define PREF_CORNERS(KK) do {                                                  \
      int ky_ = (KK) / 3, kx_ = (KK) % 3;                                      \
      float offy = meta_s[(KK) * 32 + p1];                                     \
      float offx = meta_s[288 + (KK) * 32 + p1];                               \
      float msk  = meta_s[576 + (KK) * 32 + p1];                               \
      float py = (float)(h - 1 + ky_) + offy;                                  \
      float px = (float)(w0 + p1 - 1 + kx_) + offx;                            \
      float y0f = floorf(py), x0f = floorf(px);                                \
      float ly = py - y0f, lx = px - x0f;                                      \
      int y0 = (int)y0f, x0i = (int)x0f;                                       \
      int y1 = y0 + 1, x1 = x0i + 1;                                           \
      bool vy0 = (y0 >= 0) && (y0 < HH);                                       \
      bool vy1 = (y1 >= 0) && (y1 < HH);                                       \
      bool vx0 = (x0i >= 0) && (x0i < WW);                                     \
      bool vx1 = (x1 >= 0) && (x1 < WW);                                       \
      int yc0 = min(max(y0, 0), HH - 1), yc1 = min(max(y1, 0), HH - 1);        \
      int xc0 = min(max(x0i, 0), WW - 1), xc1 = min(max(x1, 0), WW - 1);       \
      cw00 = (1.f - ly) * (1.f - lx) * ((vy0 && vx0) ? msk : 0.f);             \
      cw01 = (1.f - ly) * lx         * ((vy0 && vx1) ? msk : 0.f);             \
      cw10 = ly * (1.f - lx)         * ((vy1 && vx0) ? msk : 0.f);             \
      cw11 = ly * lx                 * ((vy1 && vx1) ? msk : 0.f);             \
      cc00 = *(const uint4*)(xbc + (size_t)(yc0 * WW + xc0) * 64);             \
      cc01 = *(const uint4*)(xbc + (size_t)(yc0 * WW + xc1) * 64);             \
      cc10 = *(const uint4*)(xbc + (size_t)(yc1 * WW + xc0) * 64);             \
      cc11 = *(const uint4*)(xbc + (size_t)(yc1 * WW + xc1) * 64);             \
    } while (0)

    PREF_CORNERS(0);

#pragma unroll
    for (int kk = 0; kk < 9; ++kk) {
        const int cur = kk & 1;
        // ---- combine (waits this tile's corners) + pack + swizzled LDS write --
        {
            char* wdst = mbase + cur * 4096;
            unsigned pk[4];
#pragma unroll
            for (int d = 0; d < 4; ++d) {
                unsigned u0 = (&cc00.x)[d], u1 = (&cc01.x)[d];
                unsigned u2 = (&cc10.x)[d], u3 = (&cc11.x)[d];
                float lo = cw00 * __builtin_bit_cast(float, u0 << 16)
                         + cw01 * __builtin_bit_cast(float, u1 << 16)
                         + cw10 * __builtin_bit_cast(float, u2 << 16)
                         + cw11 * __builtin_bit_cast(float, u3 << 16);
                float hi = cw00 * __builtin_bit_cast(float, u0 & 0xFFFF0000u)
                         + cw01 * __builtin_bit_cast(float, u1 & 0xFFFF0000u)
                         + cw10 * __builtin_bit_cast(float, u2 & 0xFFFF0000u)
                         + cw11 * __builtin_bit_cast(float, u3 & 0xFFFF0000u);
                pk[d] = (unsigned)f2bf(lo) | ((unsigned)f2bf(hi) << 16);
            }
            *(uint4*)(wdst + p1 * 128 + (((unsigned)(cg ^ (p1 & 7))) << 4)) = *(uint4*)pk;
        }

        // ---- issue NEXT tile's corner loads into the SAME regs (WAR-safe) ----
        if (kk < 8) PREF_CORNERS(kk + 1);

        // ---- raw barrier: order LDS, leave global prefetches in flight ----
        asm volatile("s_waitcnt lgkmcnt(0)" ::: "memory");
        __builtin_amdgcn_s_barrier();
        __builtin_amdgcn_sched_barrier(0);

        // ---- MFMA (tile kk); A-frags loaded inline (L2-resident wbf) ----
        const char* rb = mbase + cur * 4096;
#pragma unroll
        for (int sstep = 0; sstep < 2; ++sstep) {
            short8 a0 = *(const short8*)(arow0 + kk * 64 + sstep * 32);
            short8 a1 = *(const short8*)(arow1 + kk * 64 + sstep * 32);
            int kb = sstep * 4 + lk;
            short8 b0 = *(const short8*)(rb + rbA + ((kb ^ swA) << 4));
            short8 b1 = *(const short8*)(rb + rbB + ((kb ^ swB) << 4));
            acc00 = __builtin_amdgcn_mfma_f32_16x16x32_bf16(a0, b0, acc00, 0, 0, 0);
            acc01 = __builtin_amdgcn_mfma_f32_16x16x32_bf16(a0, b1, acc01, 0, 0, 0);
            acc10 = __builtin_amdgcn_mfma_f32_16x16x32_bf16(a1, b0, acc10, 0, 0, 0);
            acc11 = __builtin_amdgcn_mfma_f32_16x16x32_bf16(a1, b1, acc11, 0, 0, 0);
        }
    }
#undef PREF_CORNERS

    // ---- epilogue: bias + stores ----
    size_t outb = (size_t)b * COUT * HWP + (size_t)h * WW + w0;
#pragma unroll
    for (int of = 0; of < 2; ++of) {
        f32x4 aP = of ? acc10 : acc00;
        f32x4 aQ = of ? acc11 : acc01;
        int ocb = wid * 32 + of * 16 + lk * 4;
#pragma unroll
        for (int r = 0; r < 4; ++r) {
            int oc = ocb + r;
            float bi = bias[oc];
            out[outb + (size_t)oc * HWP + pA] = aP[r] + bi;
            out[outb + (size_t)oc * HWP + pB] = aQ[r] + bi;
        }
    }
}

// ================= v1 fallback (R8 kernel, validated; used if ws too small) ====
__global__ __launch_bounds__(256) void k_fused_v1(const float* __restrict__ x,
                                                  const unsigned short* __restrict__ wbf,
                                                  const unsigned short* __restrict__ owbf,
                                                  const float* __restrict__ ob,
                                                  const float* __restrict__ bias,
                                                  float* __restrict__ out) {
    __shared__ __align__(16) char smem[16768];
    char*  ctx    = smem;
    char*  mbase  = smem;
    float* meta_s = (float*)(smem + 13312);

    int blk = blockIdx.x;
    int b   = blk >> 9;
    int rem = blk & 511;
    int h   = rem >> 2;
    int w0  = (rem & 3) << 5;
    int t   = threadIdx.x;

    int p1 = t & 31;
    int cg = t >> 5;
    int l  = t & 63;
    int wid = t >> 6;
    int lm = l & 15, lk = l >> 4;

    const float* xb = x + (size_t)b * CIN * HWP;

#pragma unroll
    for (int c = 0; c < 4; ++c) {
        int j = c * 256 + t;
        if (j < 816) {
            int g   = j / 34;
            int px  = j - g * 34;
            int row = g >> 3;
            int cgj = g & 7;
            int yy = h - 1 + row;
            int xx = w0 - 1 + px;
            bool vld = (yy >= 0) && (yy < HH) && (xx >= 0) && (xx < WW);
            int  sidx = vld ? (yy * WW + xx) : 0;
            float s[8];
#pragma unroll
            for (int i = 0; i < 8; ++i)
                s[i] = vld ? xb[(size_t)(cgj * 8 + i) * HWP + sidx] : 0.f;
            uint4 pk;
            pk.x = (unsigned)f2bf(s[0]) | ((unsigned)f2bf(s[1]) << 16);
            pk.y = (unsigned)f2bf(s[2]) | ((unsigned)f2bf(s[3]) << 16);
            pk.z = (unsigned)f2bf(s[4]) | ((unsigned)f2bf(s[5]) << 16);
            pk.w = (unsigned)f2bf(s[6]) | ((unsigned)f2bf(s[7]) << 16);
            *(uint4*)(ctx + (row * 34 + px) * 128 + ((cgj ^ (px & 7)) << 4)) = pk;
        }
    }
    __syncthreads();

    int ocf = wid >> 1, pxf = wid & 1;
    int spx = pxf * 16 + lm;
    f32x4 sacc = {0.f, 0.f, 0.f, 0.f};
    const unsigned short* sab = owbf + (size_t)(ocf * 16 + lm) * 576 + lk * 8;

#pragma unroll
    for (int tap = 0; tap < 9; ++tap) {
        int ky = tap / 3, kx = tap % 3;
        int cpx = kx + spx;
        int crb = (ky * 34 + cpx) * 128;
        int csw = cpx & 7;
#pragma unroll
        for (int ch = 0; ch < 2; ++ch) {
            short8 a  = *(const short8*)(sab + tap * 64 + ch * 32);
            int kb = ch * 4 + lk;
            short8 bf = *(const short8*)(ctx + crb + (((unsigned)(kb ^ csw)) << 4));
            sacc = __builtin_amdgcn_mfma_f32_16x16x32_bf16(a, bf, sacc, 0, 0, 0);
        }
    }
#pragma unroll
    for (int r = 0; r < 4; ++r) {
        int oc = ocf * 16 + lk * 4 + r;
        if (oc < 27) {
            float v = sacc[r] + ob[oc];
            if (oc < 18) {
                meta_s[(oc & 1) * 288 + (oc >> 1) * 32 + spx] = v;
            } else {
                meta_s[2 * 288 + (oc - 18) * 32 + spx] = 1.f / (1.f + expf(-v));
            }
        }
    }
    __syncthreads();

    f32x4 acc00 = {0.f,0.f,0.f,0.f};
    f32x4 acc01 = {0.f,0.f,0.f,0.f};
    f32x4 acc10 = {0.f,0.f,0.f,0.f};
    f32x4 acc11 = {0.f,0.f,0.f,0.f};

    const unsigned short* arow0 = wbf + (size_t)(wid * 32 + lm) * 576 + lk * 8;
    const unsigned short* arow1 = arow0 + 16 * 576;

    int pA = lm, pB = lm + 16;
    int rbA = pA * 128, rbB = pB * 128;
    int swA = pA & 7,   swB = pB & 7;

    float  cw00, cw01, cw10, cw11;
    float  cc00[8], cc01[8], cc10[8], cc11[8];
    short8 na0[2], na1[2];

#define PREF_CORNERS(KK) do {                                                  \
      int ky = (KK) / 3, kx = (KK) % 3;                                        \
      float offy = meta_s[(KK) * 32 + p1];                                     \
      float offx = meta_s[288 + (KK) * 32 + p1];                               \
      float msk  = meta_s[576 + (KK) * 32 + p1];                               \
      float py = (float)(h - 1 + ky) + offy;                                   \
      float px = (float)(w0 + p1 - 1 + kx) + offx;                             \
      float y0f = floorf(py), x0f = floorf(px);                                \
      float ly = py - y0f, lx = px - x0f;                                      \
      int y0 = (int)y0f, x0i = (int)x0f;                                       \
      int y1 = y0 + 1, x1 = x0i + 1;                                           \
      bool vy0 = (y0 >= 0) && (y0 < HH);                                       \
      bool vy1 = (y1 >= 0) && (y1 < HH);                                       \
      bool vx0 = (x0i >= 0) && (x0i < WW);                                     \
      bool vx1 = (x1 >= 0) && (x1 < WW);                                       \
      int yc0 = min(max(y0, 0), HH - 1), yc1 = min(max(y1, 0), HH - 1);        \
      int xc0 = min(max(x0i, 0), WW - 1), xc1 = min(max(x1, 0), WW - 1);       \
      cw00 = (1.f - ly) * (1.f - lx) * ((vy0 && vx0) ? msk : 0.f);             \
      cw01 = (1.f - ly) * lx         * ((vy0 && vx1) ? msk : 0.f);             \
      cw10 = ly * (1.f - lx)         * ((vy1 && vx0) ? msk : 0.f);             \
      cw11 = ly * lx                 * ((vy1 && vx1) ? msk : 0.f);             \
      int idx00 = yc0 * WW + xc0, idx01 = yc0 * WW + xc1;                      \
      int idx10 = yc1 * WW + xc0, idx11 = yc1 * WW + xc1;                      \
      const float* basec = xb + (size_t)(cg * 8) * HWP;                        \
      _Pragma("unroll")                                                        \
      for (int i = 0; i < 8; ++i) {                                            \
        const float* bc = basec + (size_t)i * HWP;                             \
        cc00[i] = bc[idx00]; cc01[i] = bc[idx01];                              \
        cc10[i] = bc[idx10]; cc11[i] = bc[idx11];                              \
      }                                                                        \
    } while (0)

#define PREF_AFRAG(KK) do {                                                    \
      na0[0] = *(const short8*)(arow0 + (KK) * 64);                            \
      na0[1] = *(const short8*)(arow0 + (KK) * 64 + 32);                       \
      na1[0] = *(const short8*)(arow1 + (KK) * 64);                            \
      na1[1] = *(const short8*)(arow1 + (KK) * 64 + 32);                       \
    } while (0)

    PREF_CORNERS(0);
    PREF_AFRAG(0);

#pragma unroll
    for (int kk = 0; kk < 9; ++kk) {
        {
            char* wdst = mbase + (kk & 1) * 4096;
            float s[8];
#pragma unroll
            for (int i = 0; i < 8; ++i)
                s[i] = cw00 * cc00[i] + cw01 * cc01[i]
                     + cw10 * cc10[i] + cw11 * cc11[i];
            uint4 pk;
            pk.x = (unsigned)f2bf(s[0]) | ((unsigned)f2bf(s[1]) << 16);
            pk.y = (unsigned)f2bf(s[2]) | ((unsigned)f2bf(s[3]) << 16);
            pk.z = (unsigned)f2bf(s[4]) | ((unsigned)f2bf(s[5]) << 16);
            pk.w = (unsigned)f2bf(s[6]) | ((unsigned)f2bf(s[7]) << 16);
            *(uint4*)(wdst + p1 * 128 + (((unsigned)(cg ^ (p1 & 7))) << 4)) = pk;
        }
        if (kk < 8) PREF_CORNERS(kk + 1);
        asm volatile("s_waitcnt lgkmcnt(0)" ::: "memory");
        __builtin_amdgcn_s_barrier();
        __builtin_amdgcn_sched_barrier(0);
        const char* rb = mbase + (kk & 1) * 4096;
#pragma unroll
        for (int sstep = 0; sstep < 2; ++sstep) {
            short8 a0 = na0[sstep];
            short8 a1 = na1[sstep];
            int kb = sstep * 4 + lk;
            short8 b0 = *(const short8*)(rb + rbA + ((kb ^ swA) << 4));
            short8 b1 = *(const short8*)(rb + rbB + ((kb ^ swB) << 4));
            acc00 = __builtin_amdgcn_mfma_f32_16x16x32_bf16(a0, b0, acc00, 0, 0, 0);
            acc01 = __builtin_amdgcn_mfma_f32_16x16x32_bf16(a0, b1, acc01, 0, 0, 0);
            acc10 = __builtin_amdgcn_mfma_f32_16x16x32_bf16(a1, b0, acc10, 0, 0, 0);
            acc11 = __builtin_amdgcn_mfma_f32_16x16x32_bf16(a1, b1, acc11, 0, 0, 0);
        }
        if (kk < 8) PREF_AFRAG(kk + 1);
    }
#undef PREF_CORNERS
#undef PREF_AFRAG

    size_t outb = (size_t)b * COUT * HWP + (size_t)h * WW + w0;
#pragma unroll
    for (int of = 0; of < 2; ++of) {
        f32x4 aP = of ? acc10 : acc00;
        f32x4 aQ = of ? acc11 : acc01;
        int ocb = wid * 32 + of * 16 + lk * 4;
#pragma unroll
        for (int r = 0; r < 4; ++r) {
            int oc = ocb + r;
            float bi = bias[oc];
            out[outb + (size_t)oc * HWP + pA] = aP[r] + bi;
            out[outb + (size_t)oc * HWP + pB] = aQ[r] + bi;
        }
    }
}

extern "C" void kernel_launch(void* const* d_in, const int* in_sizes, int n_in,
                              void* d_out, int out_size, void* d_ws, size_t ws_size,
                              hipStream_t stream) {
    const float* x    = (const float*)d_in[0];
    const float* ow   = (const float*)d_in[1];
    const float* ob   = (const float*)d_in[2];
    const float* wgt  = (const float*)d_in[3];
    const float* bias = (const float*)d_in[4];
    float* out = (float*)d_out;
    char* ws = (char*)d_ws;

    unsigned short* wbf  = (unsigned short*)(ws + WBF_B);
    unsigned short* owbf = (unsigned short*)(ws + OWBF_B);
    unsigned short* xt   = (unsigned short*)(ws + XT_B);

    hipLaunchKernelGGL(k_prep_w, dim3(288), dim3(256), 0, stream, wgt, ow, wbf, owbf);
    if (ws_size >= WS_NEED) {
        hipLaunchKernelGGL(k_xt, dim3(2048), dim3(256), 0, stream, x, xt);
        hipLaunchKernelGGL(k_fused_v2, dim3(2048), dim3(256), 0, stream,
                           xt, wbf, owbf, ob, bias, out);
    } else {
        hipLaunchKernelGGL(k_fused_v1, dim3(2048), dim3(256), 0, stream,
                           x, wbf, owbf, ob, bias, out);
    }
}

// Round 17
// 92.338 us; speedup vs baseline: 1.0505x; 1.0505x over previous
//
#include <hip/hip_runtime.h>
#include <math.h>

#define HH   128
#define WW   128
#define HWP  16384      // H*W
#define CIN  64
#define COUT 128

typedef float  f32x4  __attribute__((ext_vector_type(4)));
typedef short  short8 __attribute__((ext_vector_type(8)));

// ws layout (bytes): wbf [128][576] bf16 @0 (147456); owbf [32][576] bf16 @147456
// (73728); xt NHWC bf16 [4*16384][64] @221184 (8388608). NEED = 8609792.
#define WBF_B   ((size_t)0)
#define OWBF_B  ((size_t)147456)
#define XT_B    ((size_t)221184)
#define WS_NEED ((size_t)8609792)

__device__ inline unsigned short f2bf(float f) {
    unsigned u = __builtin_bit_cast(unsigned, f);
    return (unsigned short)((u + 0x7FFFu + ((u >> 16) & 1u)) >> 16);   // RNE
}

// ---------------- fused prep: xt transpose + weight transposes (ONE launch) ----
// blocks 0..2047:   x NCHW fp32 -> xt NHWC bf16 (32 pixels/block)
// blocks 2048..2335: wbf / owbf weight transposes (288 blocks x 256 = 73728)
__global__ __launch_bounds__(256) void k_prep(const float* __restrict__ x,
                                              const float* __restrict__ wgt,
                                              const float* __restrict__ ow,
                                              unsigned short* __restrict__ xt,
                                              unsigned short* __restrict__ wbf,
                                              unsigned short* __restrict__ owbf) {
    int t = threadIdx.x;
    if (blockIdx.x < 2048) {
        int cgrp = t & 7, px = t >> 3;            // px 0..31
        int pix = blockIdx.x * 32 + px;
        int b = pix >> 14, hw = pix & 16383;
        const float* xp = x + (size_t)b * CIN * HWP + (size_t)(cgrp * 8) * HWP + hw;
        unsigned pk[4];
#pragma unroll
        for (int d = 0; d < 4; ++d) {
            float lo = xp[(size_t)(2 * d) * HWP];
            float hi = xp[(size_t)(2 * d + 1) * HWP];
            pk[d] = (unsigned)f2bf(lo) | ((unsigned)f2bf(hi) << 16);
        }
        *(uint4*)(xt + (size_t)pix * 64 + cgrp * 8) = *(uint4*)pk;
    } else {
        int tid = (blockIdx.x - 2048) * 256 + t;   // 0..73727
        {
            int oc = tid / 576;
            int r  = tid - oc * 576;
            int kk = r >> 6;
            int c  = r & 63;
            wbf[tid] = f2bf(wgt[((size_t)oc * CIN + c) * 9 + kk]);
        }
        if (tid < 32 * 576) {
            int oc  = tid / 576;
            int r   = tid - oc * 576;
            int tap = r >> 6;
            int c   = r & 63;
            owbf[tid] = (oc < 27) ? f2bf(ow[((size_t)oc * CIN + c) * 9 + tap]) : 0;
        }
    }
}

// ================= v2: NHWC-bf16 fused kernel (R16 final form) =================
// block = 32 pixels of one row x all 128 oc; 256 threads; LDS 11.6 KB
// Levers that paid (keep): NHWC-bf16 xt (R9, -27%); cg=t&7/px=t>>3 lane map
// (R11, -18%); XCD chunking (R16, FETCH 9.7->5MB). Neutral-but-harmless kept:
// single-slot pipeline (VGPR 68), inline A-frags. Plateau: 84.4us across 4
// rounds of schedule/occupancy/locality changes -> structure-bound.
__global__ __launch_bounds__(256) void k_fused_v2(const unsigned short* __restrict__ xt,
                                                  const unsigned short* __restrict__ wbf,
                                                  const unsigned short* __restrict__ owbf,
                                                  const float* __restrict__ ob,
                                                  const float* __restrict__ bias,
                                                  float* __restrict__ out) {
    __shared__ __align__(16) char smem[11648];
    char*  mbase  = smem;                    // 2 x 4KB bf16 [32p][64k] swizzled dbuf
    float* meta_s = (float*)(smem + 8192);   // [comp][kk][p] 3456B

    int blk0 = blockIdx.x;                // 2048
    int blk  = (blk0 & 7) * 256 + (blk0 >> 3);   // T1 XCD chunking
    int b   = blk >> 9;
    int rem = blk & 511;
    int h   = rem >> 2;
    int w0  = (rem & 3) << 5;
    int t   = threadIdx.x;

    int p1 = t >> 3;                      // pixel in tile (staging role)
    int cg = t & 7;                       // 8-channel group (staging role)
    int l  = t & 63;
    int wid = t >> 6;                     // wave id
    int lm = l & 15, lk = l >> 4;

    const unsigned short* xbt = xt + (size_t)b * HWP * 64;

    // ===== stage A: offset conv, B-frags DIRECT from global xt (no LDS) =====
    int ocf = wid >> 1, pxf = wid & 1;    // wave quadrant: oc[ocf*16+), px[pxf*16+)
    int spx = pxf * 16 + lm;
    f32x4 sacc = {0.f, 0.f, 0.f, 0.f};
    const unsigned short* sab = owbf + (size_t)(ocf * 16 + lm) * 576 + lk * 8;

#pragma unroll
    for (int tap = 0; tap < 9; ++tap) {
        int ky = tap / 3, kx = tap % 3;
        int yy = h - 1 + ky;
        int xx = w0 - 1 + kx + spx;
        bool vld = (yy >= 0) && (yy < HH) && (xx >= 0) && (xx < WW);
        int yc = min(max(yy, 0), HH - 1), xc = min(max(xx, 0), WW - 1);
        const unsigned short* bp = xbt + (size_t)(yc * WW + xc) * 64 + lk * 8;
#pragma unroll
        for (int ch = 0; ch < 2; ++ch) {
            short8 a = *(const short8*)(sab + tap * 64 + ch * 32);
            uint4 v = *(const uint4*)(bp + ch * 32);
            v.x = vld ? v.x : 0u;  v.y = vld ? v.y : 0u;
            v.z = vld ? v.z : 0u;  v.w = vld ? v.w : 0u;
            sacc = __builtin_amdgcn_mfma_f32_16x16x32_bf16(a, __builtin_bit_cast(short8, v), sacc, 0, 0, 0);
        }
    }
    // postprocess own quadrant -> meta_s (C map: col=lane&15 -> px, row=lk*4+r -> oc)
#pragma unroll
    for (int r = 0; r < 4; ++r) {
        int oc = ocf * 16 + lk * 4 + r;
        if (oc < 27) {
            float v = sacc[r] + ob[oc];
            if (oc < 18) {
                meta_s[(oc & 1) * 288 + (oc >> 1) * 32 + spx] = v;
            } else {
                meta_s[2 * 288 + (oc - 18) * 32 + spx] = 1.f / (1.f + expf(-v));
            }
        }
    }
    __syncthreads();   // meta_s ready

    // ================= main: pipelined bilinear (bf16x8 corners) -> MFMA =======
    f32x4 acc00 = {0.f,0.f,0.f,0.f};
    f32x4 acc01 = {0.f,0.f,0.f,0.f};
    f32x4 acc10 = {0.f,0.f,0.f,0.f};
    f32x4 acc11 = {0.f,0.f,0.f,0.f};

    const unsigned short* arow0 = wbf + (size_t)(wid * 32 + lm) * 576 + lk * 8;
    const unsigned short* arow1 = arow0 + 16 * 576;

    int pA = lm, pB = lm + 16;
    int rbA = pA * 128, rbB = pB * 128;
    int swA = pA & 7,   swB = pB & 7;

    // SINGLE-SLOT pipeline registers (R15)
    uint4 cc00, cc01, cc10, cc11;
    float cw00, cw01, cw10, cw11;

    const unsigned short* xbc = xbt + cg * 8;   // this thread's channel slice

#define PREF_CORNERS(KK) do {                                                  \
      int ky_ = (KK) / 3, kx_ = (KK) % 3;                                      \
      float offy = meta_s[(KK) * 32 + p1];                                     \
      float offx = meta_s[288 + (KK) * 32 + p1];                               \
      float msk  = meta_s[576 + (KK) * 32 + p1];                               \
      float py = (float)(h - 1 + ky_) + offy;                                  \
      float px = (float)(w0 + p1 - 1 + kx_) + offx;                            \
      float y0f = floorf(py), x0f = floorf(px);                                \
      float ly = py - y0f, lx = px - x0f;                                      \
      int y0 = (int)y0f, x0i = (int)x0f;                                       \
      int y1 = y0 + 1, x1 = x0i + 1;                                           \
      bool vy0 = (y0 >= 0) && (y0 < HH);                                       \
      bool vy1 = (y1 >= 0) && (y1 < HH);                                       \
      bool vx0 = (x0i >= 0) && (x0i < WW);                                     \
      bool vx1 = (x1 >= 0) && (x1 < WW);                                       \
      int yc0 = min(max(y0, 0), HH - 1), yc1 = min(max(y1, 0), HH - 1);        \
      int xc0 = min(max(x0i, 0), WW - 1), xc1 = min(max(x1, 0), WW - 1);       \
      cw00 = (1.f - ly) * (1.f - lx) * ((vy0 && vx0) ? msk : 0.f);             \
      cw01 = (1.f - ly) * lx         * ((vy0 && vx1) ? msk : 0.f);             \
      cw10 = ly * (1.f - lx)         * ((vy1 && vx0) ? msk : 0.f);             \
      cw11 = ly * lx                 * ((vy1 && vx1) ? msk : 0.f);             \
      cc00 = *(const uint4*)(xbc + (size_t)(yc0 * WW + xc0) * 64);             \
      cc01 = *(const uint4*)(xbc + (size_t)(yc0 * WW + xc1) * 64);             \
      cc10 = *(const uint4*)(xbc + (size_t)(yc1 * WW + xc0) * 64);             \
      cc11 = *(const uint4*)(xbc + (size_t)(yc1 * WW + xc1) * 64);             \
    } while (0)

    PREF_CORNERS(0);

#pragma unroll
    for (int kk = 0; kk < 9; ++kk) {
        const int cur = kk & 1;
        // ---- combine (waits this tile's corners) + pack + swizzled LDS write --
        {
            char* wdst = mbase + cur * 4096;
            unsigned pk[4];
#pragma unroll
            for (int d = 0; d < 4; ++d) {
                unsigned u0 = (&cc00.x)[d], u1 = (&cc01.x)[d];
                unsigned u2 = (&cc10.x)[d], u3 = (&cc11.x)[d];
                float lo = cw00 * __builtin_bit_cast(float, u0 << 16)
                         + cw01 * __builtin_bit_cast(float, u1 << 16)
                         + cw10 * __builtin_bit_cast(float, u2 << 16)
                         + cw11 * __builtin_bit_cast(float, u3 << 16);
                float hi = cw00 * __builtin_bit_cast(float, u0 & 0xFFFF0000u)
                         + cw01 * __builtin_bit_cast(float, u1 & 0xFFFF0000u)
                         + cw10 * __builtin_bit_cast(float, u2 & 0xFFFF0000u)
                         + cw11 * __builtin_bit_cast(float, u3 & 0xFFFF0000u);
                pk[d] = (unsigned)f2bf(lo) | ((unsigned)f2bf(hi) << 16);
            }
            *(uint4*)(wdst + p1 * 128 + (((unsigned)(cg ^ (p1 & 7))) << 4)) = *(uint4*)pk;
        }

        // ---- issue NEXT tile's corner loads into the SAME regs (WAR-safe) ----
        if (kk < 8) PREF_CORNERS(kk + 1);

        // ---- raw barrier: order LDS, leave global prefetches in flight ----
        asm volatile("s_waitcnt lgkmcnt(0)" ::: "memory");
        __builtin_amdgcn_s_barrier();
        __builtin_amdgcn_sched_barrier(0);

        // ---- MFMA (tile kk); A-frags loaded inline (L2-resident wbf) ----
        const char* rb = mbase + cur * 4096;
#pragma unroll
        for (int sstep = 0; sstep < 2; ++sstep) {
            short8 a0 = *(const short8*)(arow0 + kk * 64 + sstep * 32);
            short8 a1 = *(const short8*)(arow1 + kk * 64 + sstep * 32);
            int kb = sstep * 4 + lk;
            short8 b0 = *(const short8*)(rb + rbA + ((kb ^ swA) << 4));
            short8 b1 = *(const short8*)(rb + rbB + ((kb ^ swB) << 4));
            acc00 = __builtin_amdgcn_mfma_f32_16x16x32_bf16(a0, b0, acc00, 0, 0, 0);
            acc01 = __builtin_amdgcn_mfma_f32_16x16x32_bf16(a0, b1, acc01, 0, 0, 0);
            acc10 = __builtin_amdgcn_mfma_f32_16x16x32_bf16(a1, b0, acc10, 0, 0, 0);
            acc11 = __builtin_amdgcn_mfma_f32_16x16x32_bf16(a1, b1, acc11, 0, 0, 0);
        }
    }
#undef PREF_CORNERS

    // ---- epilogue: bias + stores ----
    size_t outb = (size_t)b * COUT * HWP + (size_t)h * WW + w0;
#pragma unroll
    for (int of = 0; of < 2; ++of) {
        f32x4 aP = of ? acc10 : acc00;
        f32x4 aQ = of ? acc11 : acc01;
        int ocb = wid * 32 + of * 16 + lk * 4;
#pragma unroll
        for (int r = 0; r < 4; ++r) {
            int oc = ocb + r;
            float bi = bias[oc];
            out[outb + (size_t)oc * HWP + pA] = aP[r] + bi;
            out[outb + (size_t)oc * HWP + pB] = aQ[r] + bi;
        }
    }
}

// ================= v1 fallback (R8 kernel, validated; used if ws too small) ====
__global__ __launch_bounds__(256) void k_fused_v1(const float* __restrict__ x,
                                                  const unsigned short* __restrict__ wbf,
                                                  const unsigned short* __restrict__ owbf,
                                                  const float* __restrict__ ob,
                                                  const float* __restrict__ bias,
                                                  float* __restrict__ out) {
    __shared__ __align__(16) char smem[16768];
    char*  ctx    = smem;
    char*  mbase  = smem;
    float* meta_s = (float*)(smem + 13312);

    int blk = blockIdx.x;
    int b   = blk >> 9;
    int rem = blk & 511;
    int h   = rem >> 2;
    int w0  = (rem & 3) << 5;
    int t   = threadIdx.x;

    int p1 = t & 31;
    int cg = t >> 5;
    int l  = t & 63;
    int wid = t >> 6;
    int lm = l & 15, lk = l >> 4;

    const float* xb = x + (size_t)b * CIN * HWP;

#pragma unroll
    for (int c = 0; c < 4; ++c) {
        int j = c * 256 + t;
        if (j < 816) {
            int g   = j / 34;
            int px  = j - g * 34;
            int row = g >> 3;
            int cgj = g & 7;
            int yy = h - 1 + row;
            int xx = w0 - 1 + px;
            bool vld = (yy >= 0) && (yy < HH) && (xx >= 0) && (xx < WW);
            int  sidx = vld ? (yy * WW + xx) : 0;
            float s[8];
#pragma unroll
            for (int i = 0; i < 8; ++i)
                s[i] = vld ? xb[(size_t)(cgj * 8 + i) * HWP + sidx] : 0.f;
            uint4 pk;
            pk.x = (unsigned)f2bf(s[0]) | ((unsigned)f2bf(s[1]) << 16);
            pk.y = (unsigned)f2bf(s[2]) | ((unsigned)f2bf(s[3]) << 16);
            pk.z = (unsigned)f2bf(s[4]) | ((unsigned)f2bf(s[5]) << 16);
            pk.w = (unsigned)f2bf(s[6]) | ((unsigned)f2bf(s[7]) << 16);
            *(uint4*)(ctx + (row * 34 + px) * 128 + ((cgj ^ (px & 7)) << 4)) = pk;
        }
    }
    __syncthreads();

    int ocf = wid >> 1, pxf = wid & 1;
    int spx = pxf * 16 + lm;
    f32x4 sacc = {0.f, 0.f, 0.f, 0.f};
    const unsigned short* sab = owbf + (size_t)(ocf * 16 + lm) * 576 + lk * 8;

#pragma unroll
    for (int tap = 0; tap < 9; ++tap) {
        int ky = tap / 3, kx = tap % 3;
        int cpx = kx + spx;
        int crb = (ky * 34 + cpx) * 128;
        int csw = cpx & 7;
#pragma unroll
        for (int ch = 0; ch < 2; ++ch) {
            short8 a  = *(const short8*)(sab + tap * 64 + ch * 32);
            int kb = ch * 4 + lk;
            short8 bf = *(const short8*)(ctx + crb + (((unsigned)(kb ^ csw)) << 4));
            sacc = __builtin_amdgcn_mfma_f32_16x16x32_bf16(a, bf, sacc, 0, 0, 0);
        }
    }
#pragma unroll
    for (int r = 0; r < 4; ++r) {
        int oc = ocf * 16 + lk * 4 + r;
        if (oc < 27) {
            float v = sacc[r] + ob[oc];
            if (oc < 18) {
                meta_s[(oc & 1) * 288 + (oc >> 1) * 32 + spx] = v;
            } else {
                meta_s[2 * 288 + (oc - 18) * 32 + spx] = 1.f / (1.f + expf(-v));
            }
        }
    }
    __syncthreads();

    f32x4 acc00 = {0.f,0.f,0.f,0.f};
    f32x4 acc01 = {0.f,0.f,0.f,0.f};
    f32x4 acc10 = {0.f,0.f,0.f,0.f};
    f32x4 acc11 = {0.f,0.f,0.f,0.f};

    const unsigned short* arow0 = wbf + (size_t)(wid * 32 + lm) * 576 + lk * 8;
    const unsigned short* arow1 = arow0 + 16 * 576;

    int pA = lm, pB = lm + 16;
    int rbA = pA * 128, rbB = pB * 128;
    int swA = pA & 7,   swB = pB & 7;

    float  cw00, cw01, cw10, cw11;
    float  cc00[8], cc01[8], cc10[8], cc11[8];
    short8 na0[2], na1[2];

#define PREF_CORNERS(KK) do {                                                  \
      int ky = (KK) / 3, kx = (KK) % 3;                                        \
      float offy = meta_s[(KK) * 32 + p1];                                     \
      float offx = meta_s[288 + (KK) * 32 + p1];                               \
      float msk  = meta_s[576 + (KK) * 32 + p1];                               \
      float py = (float)(h - 1 + ky) + offy;                                   \
      float px = (float)(w0 + p1 - 1 + kx) + offx;                             \
      float y0f = floorf(py), x0f = floorf(px);                                \
      float ly = py - y0f, lx = px - x0f;                                      \
      int y0 = (int)y0f, x0i = (int)x0f;                                       \
      int y1 = y0 + 1, x1 = x0i + 1;                                           \
      bool vy0 = (y0 >= 0) && (y0 < HH);                                       \
      bool vy1 = (y1 >= 0) && (y1 < HH);                                       \
      bool vx0 = (x0i >= 0) && (x0i < WW);                                     \
      bool vx1 = (x1 >= 0) && (x1 < WW);                                       \
      int yc0 = min(max(y0, 0), HH - 1), yc1 = min(max(y1, 0), HH - 1);        \
      int xc0 = min(max(x0i, 0), WW - 1), xc1 = min(max(x1, 0), WW - 1);       \
      cw00 = (1.f - ly) * (1.f - lx) * ((vy0 && vx0) ? msk : 0.f);             \
      cw01 = (1.f - ly) * lx         * ((vy0 && vx1) ? msk : 0.f);             \
      cw10 = ly * (1.f - lx)         * ((vy1 && vx0) ? msk : 0.f);             \
      cw11 = ly * lx                 * ((vy1 && vx1) ? msk : 0.f);             \
      int idx00 = yc0 * WW + xc0, idx01 = yc0 * WW + xc1;                      \
      int idx10 = yc1 * WW + xc0, idx11 = yc1 * WW + xc1;                      \
      const float* basec = xb + (size_t)(cg * 8) * HWP;                        \
      _Pragma("unroll")                                                        \
      for (int i = 0; i < 8; ++i) {                                            \
        const float* bc = basec + (size_t)i * HWP;                             \
        cc00[i] = bc[idx00]; cc01[i] = bc[idx01];                              \
        cc10[i] = bc[idx10]; cc11[i] = bc[idx11];                              \
      }                                                                        \
    } while (0)

#define PREF_AFRAG(KK) do {                                                    \
      na0[0] = *(const short8*)(arow0 + (KK) * 64);                            \
      na0[1] = *(const short8*)(arow0 + (KK) * 64 + 32);                       \
      na1[0] = *(const short8*)(arow1 + (KK) * 64);                            \
      na1[1] = *(const short8*)(arow1 + (KK) * 64 + 32);                       \
    } while (0)

    PREF_CORNERS(0);
    PREF_AFRAG(0);

#pragma unroll
    for (int kk = 0; kk < 9; ++kk) {
        {
            char* wdst = mbase + (kk & 1) * 4096;
            float s[8];
#pragma unroll
            for (int i = 0; i < 8; ++i)
                s[i] = cw00 * cc00[i] + cw01 * cc01[i]
                     + cw10 * cc10[i] + cw11 * cc11[i];
            uint4 pk;
            pk.x = (unsigned)f2bf(s[0]) | ((unsigned)f2bf(s[1]) << 16);
            pk.y = (unsigned)f2bf(s[2]) | ((unsigned)f2bf(s[3]) << 16);
            pk.z = (unsigned)f2bf(s[4]) | ((unsigned)f2bf(s[5]) << 16);
            pk.w = (unsigned)f2bf(s[6]) | ((unsigned)f2bf(s[7]) << 16);
            *(uint4*)(wdst + p1 * 128 + (((unsigned)(cg ^ (p1 & 7))) << 4)) = pk;
        }
        if (kk < 8) PREF_CORNERS(kk + 1);
        asm volatile("s_waitcnt lgkmcnt(0)" ::: "memory");
        __builtin_amdgcn_s_barrier();
        __builtin_amdgcn_sched_barrier(0);
        const char* rb = mbase + (kk & 1) * 4096;
#pragma unroll
        for (int sstep = 0; sstep < 2; ++sstep) {
            short8 a0 = na0[sstep];
            short8 a1 = na1[sstep];
            int kb = sstep * 4 + lk;
            short8 b0 = *(const short8*)(rb + rbA + ((kb ^ swA) << 4));
            short8 b1 = *(const short8*)(rb + rbB + ((kb ^ swB) << 4));
            acc00 = __builtin_amdgcn_mfma_f32_16x16x32_bf16(a0, b0, acc00, 0, 0, 0);
            acc01 = __builtin_amdgcn_mfma_f32_16x16x32_bf16(a0, b1, acc01, 0, 0, 0);
            acc10 = __builtin_amdgcn_mfma_f32_16x16x32_bf16(a1, b0, acc10, 0, 0, 0);
            acc11 = __builtin_amdgcn_mfma_f32_16x16x32_bf16(a1, b1, acc11, 0, 0, 0);
        }
        if (kk < 8) PREF_AFRAG(kk + 1);
    }
#undef PREF_CORNERS
#undef PREF_AFRAG

    size_t outb = (size_t)b * COUT * HWP + (size_t)h * WW + w0;
#pragma unroll
    for (int of = 0; of < 2; ++of) {
        f32x4 aP = of ? acc10 : acc00;
        f32x4 aQ = of ? acc11 : acc01;
        int ocb = wid * 32 + of * 16 + lk * 4;
#pragma unroll
        for (int r = 0; r < 4; ++r) {
            int oc = ocb + r;
            float bi = bias[oc];
            out[outb + (size_t)oc * HWP + pA] = aP[r] + bi;
            out[outb + (size_t)oc * HWP + pB] = aQ[r] + bi;
        }
    }
}

extern "C" void kernel_launch(void* const* d_in, const int* in_sizes, int n_in,
                              void* d_out, int out_size, void* d_ws, size_t ws_size,
                              hipStream_t stream) {
    const float* x    = (const float*)d_in[0];
    const float* ow   = (const float*)d_in[1];
    const float* ob   = (const float*)d_in[2];
    const float* wgt  = (const float*)d_in[3];
    const float* bias = (const float*)d_in[4];
    float* out = (float*)d_out;
    char* ws = (char*)d_ws;

    unsigned short* wbf  = (unsigned short*)(ws + WBF_B);
    unsigned short* owbf = (unsigned short*)(ws + OWBF_B);
    unsigned short* xt   = (unsigned short*)(ws + XT_B);

    if (ws_size >= WS_NEED) {
        hipLaunchKernelGGL(k_prep, dim3(2336), dim3(256), 0, stream,
                           x, wgt, ow, xt, wbf, owbf);
        hipLaunchKernelGGL(k_fused_v2, dim3(2048), dim3(256), 0, stream,
                           xt, wbf, owbf, ob, bias, out);
    } else {
        // fallback path: weight preps only (fit in small ws), v1 reads x directly
        hipLaunchKernelGGL(k_prep, dim3(2336), dim3(256), 0, stream,
                           x, wgt, ow, xt, wbf, owbf);   // xt region unused below
        hipLaunchKernelGGL(k_fused_v1, dim3(2048), dim3(256), 0, stream,
                           x, wbf, owbf, ob, bias, out);
    }
}